// Round 8
// baseline (252.745 us; speedup 1.0000x reference)
//
#include <hip/hip_runtime.h>

// ---------------------------------------------------------------------------
// MultiHeadAttention: x(4,2048,512) fp32, adj(4,2048,2048) 0/1 fp32
// R8: split-K attention. grid 1024 (2 key-halves), 4 blocks/CU (was 2) for
// 2x latency hiding. No online max => partials combine additively: fp32
// atomicAdd of unnormalized O and l into ws; gemm1 A-staging divides by l.
// Of overlays dead x_bf region; memsetAsync zeroes it after gemm0.
// ---------------------------------------------------------------------------

typedef __attribute__((ext_vector_type(8))) short bf16x8;
typedef __attribute__((ext_vector_type(4))) float f32x4;
typedef __attribute__((ext_vector_type(4))) unsigned short ushort4v;
typedef __attribute__((ext_vector_type(4))) _Float16 f16x4;

#if __has_builtin(__builtin_amdgcn_exp2f)
#define EXP2F(x) __builtin_amdgcn_exp2f(x)
#else
#define EXP2F(x) exp2f(x)
#endif

// 0.125 (1/sqrt(64)) * log2(e), folded into Q at the QKV-gemm epilogue
#define QSCALE 0.18033688011112042f

__device__ __forceinline__ unsigned short f2bf(float f) {
  unsigned int u = __float_as_uint(f);
  u += 0x7FFFu + ((u >> 16) & 1u);
  return (unsigned short)(u >> 16);
}
__device__ __forceinline__ unsigned short f2h(float f) {
  union { _Float16 h; unsigned short u; } cv;
  cv.h = (_Float16)f;
  return cv.u;
}

// ---------------- fused prep: casts + adj bit-pack, one launch ---------------
__global__ __launch_bounds__(256) void prep_k(const float* __restrict__ x,
                                              unsigned short* __restrict__ x_bf,
                                              const float* __restrict__ wqkv,
                                              unsigned short* __restrict__ wqkv_bf,
                                              const float* __restrict__ outw,
                                              unsigned short* __restrict__ outw_bf,
                                              const float* __restrict__ adj,
                                              unsigned long long* __restrict__ abits) {
  const int bid = blockIdx.x;
  if (bid < 5120) {
    const float* in; unsigned short* out; int i;
    if (bid < 4096) { in = x; out = x_bf; i = bid * 256 + threadIdx.x; }
    else if (bid < 4864) { in = wqkv; out = wqkv_bf; i = (bid - 4096) * 256 + threadIdx.x; }
    else { in = outw; out = outw_bf; i = (bid - 4864) * 256 + threadIdx.x; }
    float4 v = ((const float4*)in)[i];
    ushort4v o;
    o[0] = f2bf(v.x); o[1] = f2bf(v.y); o[2] = f2bf(v.z); o[3] = f2bf(v.w);
    ((ushort4v*)out)[i] = o;
  } else {
    const int gw = (bid - 5120) * 4 + (threadIdx.x >> 6);  // 0..8191 = b*2048+q
    const int l = threadIdx.x & 63;
    const int b = gw >> 11, q = gw & 2047;
    const float* row = adj + ((size_t)b * 2048 + q) * 2048;
    unsigned long long* ob = abits + (size_t)b * 65536 + q;
#pragma unroll 4
    for (int kt = 0; kt < 32; ++kt) {
      const float v = row[kt * 64 + l];
      const unsigned long long m = __ballot(v != 0.f);
      if (l == 0) ob[(size_t)kt * 2048] = m;
    }
  }
}

// ---------------- 128x128 bf16 MFMA GEMM: C = A @ Bt^T (+bias) ----------------
// Double-buffered LDS, one barrier/iter; next-chunk loads issued pre-compute.
// MODE 0: A = bf16. QKV epilogue (Q scaled bf16 / K bf16 / V f16 transposed).
// MODE 1: A = fp32 Of normalized by Lf at staging; fp32+bias epilogue.
template <int MODE>
__global__ __launch_bounds__(256, 3) void gemm128_k(const unsigned short* __restrict__ A,
                                                    const unsigned short* __restrict__ Bt,
                                                    const float* __restrict__ bias, int Kdim,
                                                    int Ntiles, unsigned short* __restrict__ q_out,
                                                    unsigned short* __restrict__ k_out,
                                                    unsigned short* __restrict__ v_out,
                                                    float* __restrict__ f_out,
                                                    const float* __restrict__ Of,
                                                    const float* __restrict__ Lf) {
  __shared__ union {
    struct { unsigned short A[2][128][40], B[2][128][40]; } s;  // 40 KB
    unsigned short T[64][136];                                  // V-transpose staging
  } u;

  const int t = threadIdx.x;
  const int lane = t & 63, w = t >> 6, ln = lane & 15, quad = lane >> 4;
  const int mt = blockIdx.x / Ntiles, nt = blockIdx.x % Ntiles;
  const int wm = (w >> 1) * 64, wn = (w & 1) * 64;
  const int strow = t >> 2, stcol = (t & 3) * 8;

  const size_t abase = (size_t)(mt * 128 + strow) * Kdim + stcol;
  const size_t bbase = (size_t)(nt * 128 + strow) * Kdim + stcol;

  // MODE 1: A element = Of[m][c] * (1/l[b,h,s]) cast to bf16
  auto ldA1 = [&](int mrow, int c) -> bf16x8 {
    const float4 p0 = *(const float4*)(Of + (size_t)mrow * 512 + c);
    const float4 p1 = *(const float4*)(Of + (size_t)mrow * 512 + c + 4);
    const int bb = mrow >> 11, sq = mrow & 2047, hh = c >> 6;
    const float li = 1.0f / Lf[((bb << 3) + hh) * 2048 + sq];
    bf16x8 r;
    r[0] = (short)f2bf(p0.x * li); r[1] = (short)f2bf(p0.y * li);
    r[2] = (short)f2bf(p0.z * li); r[3] = (short)f2bf(p0.w * li);
    r[4] = (short)f2bf(p1.x * li); r[5] = (short)f2bf(p1.y * li);
    r[6] = (short)f2bf(p1.z * li); r[7] = (short)f2bf(p1.w * li);
    return r;
  };
  const int mrow0 = mt * 128 + strow, mrow1 = mt * 128 + 64 + strow;

  f32x4 acc[4][4];
#pragma unroll
  for (int i = 0; i < 4; ++i)
#pragma unroll
    for (int j = 0; j < 4; ++j) acc[i][j] = (f32x4){0.f, 0.f, 0.f, 0.f};

  // prologue: load + stage chunk 0 into buf 0
  bf16x8 a0, a1;
  if (MODE == 0) {
    a0 = *(const bf16x8*)(A + abase);
    a1 = *(const bf16x8*)(A + abase + (size_t)64 * Kdim);
  } else {
    a0 = ldA1(mrow0, stcol);
    a1 = ldA1(mrow1, stcol);
  }
  bf16x8 b0 = *(const bf16x8*)(Bt + bbase);
  bf16x8 b1 = *(const bf16x8*)(Bt + bbase + (size_t)64 * Kdim);
  *(bf16x8*)&u.s.A[0][strow][stcol] = a0;
  *(bf16x8*)&u.s.A[0][64 + strow][stcol] = a1;
  *(bf16x8*)&u.s.B[0][strow][stcol] = b0;
  *(bf16x8*)&u.s.B[0][64 + strow][stcol] = b1;
  __syncthreads();

  const int iters = Kdim >> 5;
  for (int it = 0; it < iters; ++it) {
    const int cur = it & 1, nxt = cur ^ 1;

    // issue next-chunk loads FIRST (drained at the LDS write below)
    const int kn = ((it + 1) << 5) & (Kdim - 1);
    if (MODE == 0) {
      a0 = *(const bf16x8*)(A + abase + kn);
      a1 = *(const bf16x8*)(A + abase + (size_t)64 * Kdim + kn);
    } else {
      a0 = ldA1(mrow0, stcol + kn);
      a1 = ldA1(mrow1, stcol + kn);
    }
    b0 = *(const bf16x8*)(Bt + bbase + kn);
    b1 = *(const bf16x8*)(Bt + bbase + (size_t)64 * Kdim + kn);

    bf16x8 bfr[4];
#pragma unroll
    for (int nf = 0; nf < 4; ++nf)
      bfr[nf] = *(const bf16x8*)&u.s.B[cur][wn + nf * 16 + ln][quad * 8];
#pragma unroll
    for (int mf = 0; mf < 4; ++mf) {
      bf16x8 af = *(const bf16x8*)&u.s.A[cur][wm + mf * 16 + ln][quad * 8];
#pragma unroll
      for (int nf = 0; nf < 4; ++nf)
        acc[mf][nf] = __builtin_amdgcn_mfma_f32_16x16x32_bf16(af, bfr[nf], acc[mf][nf], 0, 0, 0);
    }

    if (it + 1 < iters) {
      *(bf16x8*)&u.s.A[nxt][strow][stcol] = a0;
      *(bf16x8*)&u.s.A[nxt][64 + strow][stcol] = a1;
      *(bf16x8*)&u.s.B[nxt][strow][stcol] = b0;
      *(bf16x8*)&u.s.B[nxt][64 + strow][stcol] = b1;
      __syncthreads();
    }
  }

  // ---------------- epilogue (C layout: col=lane&15, row=quad*4+reg) ----------
  if (MODE == 0 && nt >= 8) {
    // V: LDS transpose -> coalesced V^T rows. Tile = 128 s x 128 d-cols.
    const int bb = mt >> 4, sq0 = (mt & 15) * 128;
#pragma unroll
    for (int half = 0; half < 2; ++half) {
      __syncthreads();  // A/B buffers dead; T aliases them
      if ((w & 1) == half) {
#pragma unroll
        for (int nf = 0; nf < 4; ++nf) {
          const float bv = bias[nt * 128 + half * 64 + nf * 16 + ln];
#pragma unroll
          for (int mf = 0; mf < 4; ++mf)
#pragma unroll
            for (int r = 0; r < 4; ++r)
              u.T[nf * 16 + ln][wm + mf * 16 + quad * 4 + r] = f2h(acc[mf][nf][r] + bv);
        }
      }
      __syncthreads();
#pragma unroll
      for (int rep = 0; rep < 4; ++rep) {
        const int row = rep * 16 + (t >> 4), c = t & 15;
        const bf16x8 val = *(const bf16x8*)&u.T[row][c * 8];
        const int hd = (nt - 8) * 128 + half * 64 + row;
        const int hh = hd >> 6, dd = hd & 63;
        *(bf16x8*)(v_out + ((size_t)(bb * 8 + hh) * 64 + dd) * 2048 + sq0 + c * 8) = val;
      }
    }
    return;
  }

#pragma unroll
  for (int mf = 0; mf < 4; ++mf) {
    const int m = mt * 128 + wm + mf * 16 + quad * 4;
#pragma unroll
    for (int nf = 0; nf < 4; ++nf) {
      const int n = nt * 128 + wn + nf * 16 + ln;
      const float bv = bias[n];
      if (MODE == 0) {
        const int hd = n & 511;
        const int hh = hd >> 6, dd = hd & 63;
        const int bb = m >> 11, sq = m & 2047;
        if (n < 512) {
#pragma unroll
          for (int r = 0; r < 4; ++r)
            q_out[((size_t)(bb * 8 + hh) * 2048 + sq + r) * 64 + dd] =
                f2bf((acc[mf][nf][r] + bv) * QSCALE);
        } else {
#pragma unroll
          for (int r = 0; r < 4; ++r)
            k_out[((size_t)(bb * 8 + hh) * 2048 + sq + r) * 64 + dd] = f2bf(acc[mf][nf][r] + bv);
        }
      } else {
#pragma unroll
        for (int r = 0; r < 4; ++r) f_out[(size_t)(m + r) * 512 + n] = acc[mf][nf][r] + bv;
      }
    }
  }
}

// ---------------- fused flash attention, split-K, S^T orientation -----------
// grid 1024: bh = blk&31, qt = (blk>>5)&15, half = blk>>9 (16 k-tiles each).
// Partials: atomicAdd fp32 unnormalized O into Of(b,s,e), l into Lf(bh,s).
__global__ __launch_bounds__(256, 4) void attn_k(const unsigned short* __restrict__ Qg,
                                                 const unsigned short* __restrict__ Kg,
                                                 const unsigned short* __restrict__ Vg,
                                                 const unsigned long long* __restrict__ Mg,
                                                 float* __restrict__ Of,
                                                 float* __restrict__ Lf) {
  __shared__ unsigned short K_lds[2][64][72];   // [buf][key][d] bf16
  __shared__ unsigned short V_lds[2][64][72];   // [buf][d][key] f16
  __shared__ unsigned long long M_lds[2][128];  // [buf][q] mask bits

  const int t = threadIdx.x;
  const int w = t >> 6, lane = t & 63, ln = lane & 15, quad = lane >> 4;
  const int bh = blockIdx.x & 31, qt = (blockIdx.x >> 5) & 15, half = blockIdx.x >> 9;
  const int bb = bh >> 3;
  const int sbase = qt * 128;
  const int kt0 = half * 16;

  const unsigned short* Qp = Qg + (size_t)bh * (2048 * 64);
  const unsigned short* Kp = Kg + (size_t)bh * (2048 * 64);
  const unsigned short* Vp = Vg + (size_t)bh * (64 * 2048);
  const unsigned long long* Mp = Mg + (size_t)bb * 65536 + sbase;

  bf16x8 qf[2][2];
#pragma unroll
  for (int qg = 0; qg < 2; ++qg) {
    const int qrow = sbase + w * 32 + qg * 16 + ln;
    qf[qg][0] = *(const bf16x8*)(Qp + (size_t)qrow * 64 + quad * 8);
    qf[qg][1] = *(const bf16x8*)(Qp + (size_t)qrow * 64 + 32 + quad * 8);
  }

  // ones-column B-frag: B[k][n]=1 iff n==0 -> lane ln==0 holds ones
  const _Float16 one_h = (_Float16)((ln == 0) ? 1.0f : 0.0f);
  const f16x4 vf_one = (f16x4){one_h, one_h, one_h, one_h};

  f32x4 acc_o[2][4];
#pragma unroll
  for (int qg = 0; qg < 2; ++qg)
#pragma unroll
    for (int dg = 0; dg < 4; ++dg) acc_o[qg][dg] = (f32x4){0.f, 0.f, 0.f, 0.f};
  f32x4 acc_1[2] = {(f32x4){0.f, 0.f, 0.f, 0.f}, (f32x4){0.f, 0.f, 0.f, 0.f}};

  const int strow = t >> 2;
  const int stcol = (t & 3) * 16;

  // prologue: load tile kt0 into buf 0
  {
    const int k0 = kt0 * 64;
    bf16x8 kr0 = *(const bf16x8*)(Kp + (size_t)(k0 + strow) * 64 + stcol);
    bf16x8 kr1 = *(const bf16x8*)(Kp + (size_t)(k0 + strow) * 64 + stcol + 8);
    bf16x8 vr0 = *(const bf16x8*)(Vp + (size_t)strow * 2048 + k0 + stcol);
    bf16x8 vr1 = *(const bf16x8*)(Vp + (size_t)strow * 2048 + k0 + stcol + 8);
    unsigned long long mreg = (w < 2) ? Mp[(size_t)kt0 * 2048 + w * 64 + lane] : 0ull;
    *(bf16x8*)&K_lds[0][strow][stcol] = kr0;
    *(bf16x8*)&K_lds[0][strow][stcol + 8] = kr1;
    *(bf16x8*)&V_lds[0][strow][stcol] = vr0;
    *(bf16x8*)&V_lds[0][strow][stcol + 8] = vr1;
    if (w < 2) M_lds[0][w * 64 + lane] = mreg;
  }
  __syncthreads();

  for (int ktl = 0; ktl < 16; ++ktl) {
    const int cur = ktl & 1, nxt = cur ^ 1;

    // next-tile global loads (drained at the LDS writes below)
    const int ktn = kt0 + ((ktl + 1) & 15);
    const int k0n = ktn * 64;
    bf16x8 kr0 = *(const bf16x8*)(Kp + (size_t)(k0n + strow) * 64 + stcol);
    bf16x8 kr1 = *(const bf16x8*)(Kp + (size_t)(k0n + strow) * 64 + stcol + 8);
    bf16x8 vr0 = *(const bf16x8*)(Vp + (size_t)strow * 2048 + k0n + stcol);
    bf16x8 vr1 = *(const bf16x8*)(Vp + (size_t)strow * 2048 + k0n + stcol + 8);
    unsigned long long mreg = (w < 2) ? Mp[(size_t)ktn * 2048 + w * 64 + lane] : 0ull;

    // S^T[key][q] : A = K-frag, B = Q-frag
    f32x4 sc[2][4];
#pragma unroll
    for (int nf = 0; nf < 4; ++nf) {
      bf16x8 kf0 = *(const bf16x8*)&K_lds[cur][nf * 16 + ln][quad * 8];
      bf16x8 kf1 = *(const bf16x8*)&K_lds[cur][nf * 16 + ln][32 + quad * 8];
#pragma unroll
      for (int qg = 0; qg < 2; ++qg) {
        f32x4 z = (f32x4){0.f, 0.f, 0.f, 0.f};
        z = __builtin_amdgcn_mfma_f32_16x16x32_bf16(kf0, qf[qg][0], z, 0, 0, 0);
        sc[qg][nf] = __builtin_amdgcn_mfma_f32_16x16x32_bf16(kf1, qf[qg][1], z, 0, 0, 0);
      }
    }

    // hoist ALL V-frag LDS reads; lgkm waits overlap the exp burst below
    f16x4 vfa[4][4];
#pragma unroll
    for (int ks = 0; ks < 4; ++ks)
#pragma unroll
      for (int dg = 0; dg < 4; ++dg)
        vfa[ks][dg] = *(const f16x4*)&V_lds[cur][dg * 16 + ln][ks * 16 + quad * 4];

    // mask + exp2 -> P in f16 A-frag layout (A[m=ln][k=quad*4+j])
    f16x4 pa[2][4];
#pragma unroll
    for (int qg = 0; qg < 2; ++qg) {
      const unsigned long long m64 = M_lds[cur][w * 32 + qg * 16 + ln];
#pragma unroll
      for (int nf = 0; nf < 4; ++nf) {
        const unsigned nib = (unsigned)(m64 >> (nf * 16 + quad * 4)) & 0xFu;
#pragma unroll
        for (int r = 0; r < 4; ++r) {
          const float s = (nib >> r) & 1u ? sc[qg][nf][r] : 0.f;
          pa[qg][nf][r] = (_Float16)EXP2F(s);
        }
      }
    }

    // O += P @ V ; lsum += P @ ones (col 0 of acc_1)
#pragma unroll
    for (int ks = 0; ks < 4; ++ks)
#pragma unroll
      for (int qg = 0; qg < 2; ++qg) {
#pragma unroll
        for (int dg = 0; dg < 4; ++dg)
          acc_o[qg][dg] =
              __builtin_amdgcn_mfma_f32_16x16x16f16(pa[qg][ks], vfa[ks][dg], acc_o[qg][dg], 0, 0, 0);
        acc_1[qg] = __builtin_amdgcn_mfma_f32_16x16x16f16(pa[qg][ks], vf_one, acc_1[qg], 0, 0, 0);
      }

    if (ktl < 15) {
      *(bf16x8*)&K_lds[nxt][strow][stcol] = kr0;
      *(bf16x8*)&K_lds[nxt][strow][stcol + 8] = kr1;
      *(bf16x8*)&V_lds[nxt][strow][stcol] = vr0;
      *(bf16x8*)&V_lds[nxt][strow][stcol + 8] = vr1;
      if (w < 2) M_lds[nxt][w * 64 + lane] = mreg;
      __syncthreads();
    }
  }

  // epilogue: atomic-accumulate unnormalized partials.
  // O rows q=quad*4+r, cols d=dg*16+ln ; l rows live in acc_1[qg][r] @ ln==0
  float* Ofp = Of + (size_t)bb * 2048 * 512 + (size_t)(bh & 7) * 64;
#pragma unroll
  for (int qg = 0; qg < 2; ++qg)
#pragma unroll
    for (int r = 0; r < 4; ++r) {
      const int sq = sbase + w * 32 + qg * 16 + quad * 4 + r;
#pragma unroll
      for (int dg = 0; dg < 4; ++dg)
        atomicAdd(&Ofp[(size_t)sq * 512 + dg * 16 + ln], acc_o[qg][dg][r]);
    }
  if (ln == 0) {
    float* Lfp = Lf + bh * 2048;
#pragma unroll
    for (int qg = 0; qg < 2; ++qg)
#pragma unroll
      for (int r = 0; r < 4; ++r)
        atomicAdd(&Lfp[sbase + w * 32 + qg * 16 + quad * 4 + r], acc_1[qg][r]);
  }
}

// ---------------------------------------------------------------------------
extern "C" void kernel_launch(void* const* d_in, const int* in_sizes, int n_in, void* d_out,
                              int out_size, void* d_ws, size_t ws_size, hipStream_t stream) {
  const float* x = (const float*)d_in[0];
  const float* adj = (const float*)d_in[1];
  const float* wqkv = (const float*)d_in[2];
  const float* bqkv = (const float*)d_in[3];
  const float* outw = (const float*)d_in[4];
  const float* outb = (const float*)d_in[5];
  float* out = (float*)d_out;

  char* ws = (char*)d_ws;
  // [0,16MB): x_bf[0,8) + wqkv_bf[8,9.5) during prep/gemm0; Of fp32 after.
  unsigned short* x_bf = (unsigned short*)(ws);
  unsigned short* wqkv_bf = (unsigned short*)(ws + 8388608);
  float* Of = (float*)(ws);                                        // 16 MB (4,2048,512) fp32
  float* Lf = (float*)(ws + 16777216);                             // 256 KB (32,2048) fp32
  unsigned short* outw_bf = (unsigned short*)(ws + 17301504);      // 0.5 MB
  unsigned long long* abits = (unsigned long long*)(ws + 17825792);  // 2 MB
  unsigned short* Qb = (unsigned short*)(ws + 19922944);           // 8 MB (b,h,s,d) bf16
  unsigned short* Kb = (unsigned short*)(ws + 28311552);           // 8 MB (b,h,s,d) bf16
  unsigned short* Vb = (unsigned short*)(ws + 36700160);           // 8 MB (b,h,d,s) f16
  // end: 45088768 bytes = 43 MB (< proven 58 MB)

  prep_k<<<7168, 256, 0, stream>>>(x, x_bf, wqkv, wqkv_bf, outw, outw_bf, adj, abits);

  gemm128_k<0><<<768, 256, 0, stream>>>(x_bf, wqkv_bf, bqkv, 512, 12, Qb, Kb, Vb, nullptr,
                                        nullptr, nullptr);

  // zero the fp32 accumulators (x_bf/wqkv_bf are dead now)
  hipMemsetAsync(Of, 0, 16777216 + 524288, stream);

  attn_k<<<1024, 256, 0, stream>>>(Qb, Kb, Vb, abits, Of, Lf);

  gemm128_k<1><<<256, 256, 0, stream>>>(nullptr, outw_bf, outb, 512, 4, nullptr, nullptr, nullptr,
                                        out, Of, Lf);
}

// Round 10
// 220.105 us; speedup vs baseline: 1.1483x; 1.1483x over previous
//
#include <hip/hip_runtime.h>

// ---------------------------------------------------------------------------
// MultiHeadAttention: x(4,2048,512) fp32, adj(4,2048,2048) 0/1 fp32
// R10 (= R9 with cvt_pkrtz type fix): revert split-K; R7 base + VALU cuts:
// sbfe sign-mask, packed cvt_pkrtz f32->f16, linear prefetch addressing.
// ---------------------------------------------------------------------------

typedef __attribute__((ext_vector_type(8))) short bf16x8;
typedef __attribute__((ext_vector_type(4))) float f32x4;
typedef __attribute__((ext_vector_type(4))) unsigned short ushort4v;
typedef __attribute__((ext_vector_type(4))) _Float16 f16x4;
typedef __attribute__((ext_vector_type(2))) __fp16 h16x2;  // cvt_pkrtz return type

#if __has_builtin(__builtin_amdgcn_exp2f)
#define EXP2F(x) __builtin_amdgcn_exp2f(x)
#else
#define EXP2F(x) exp2f(x)
#endif

// 0.125 (1/sqrt(64)) * log2(e), folded into Q at the QKV-gemm epilogue
#define QSCALE 0.18033688011112042f

__device__ __forceinline__ unsigned short f2bf(float f) {
  unsigned int u = __float_as_uint(f);
  u += 0x7FFFu + ((u >> 16) & 1u);
  return (unsigned short)(u >> 16);
}
__device__ __forceinline__ unsigned short f2h(float f) {
  union { _Float16 h; unsigned short u; } cv;
  cv.h = (_Float16)f;
  return cv.u;
}

// sign-extend bit (pos) of w to 0 / 0xFFFFFFFF
__device__ __forceinline__ int sbit(unsigned w, int pos) {
  return ((int)(w << (31 - pos))) >> 31;  // compiler emits v_bfe_i32
}

// pack 4 floats -> f16x4 via 2 packed RTZ converts
__device__ __forceinline__ f16x4 pk4(float p0, float p1, float p2, float p3) {
  union { struct { h16x2 a, b; } s; f16x4 v; } u;
  u.s.a = __builtin_amdgcn_cvt_pkrtz(p0, p1);
  u.s.b = __builtin_amdgcn_cvt_pkrtz(p2, p3);
  return u.v;
}

// ---------------- fused prep: casts + adj bit-pack, one launch ---------------
__global__ __launch_bounds__(256) void prep_k(const float* __restrict__ x,
                                              unsigned short* __restrict__ x_bf,
                                              const float* __restrict__ wqkv,
                                              unsigned short* __restrict__ wqkv_bf,
                                              const float* __restrict__ outw,
                                              unsigned short* __restrict__ outw_bf,
                                              const float* __restrict__ adj,
                                              unsigned long long* __restrict__ abits) {
  const int bid = blockIdx.x;
  if (bid < 5120) {
    const float* in; unsigned short* out; int i;
    if (bid < 4096) { in = x; out = x_bf; i = bid * 256 + threadIdx.x; }
    else if (bid < 4864) { in = wqkv; out = wqkv_bf; i = (bid - 4096) * 256 + threadIdx.x; }
    else { in = outw; out = outw_bf; i = (bid - 4864) * 256 + threadIdx.x; }
    float4 v = ((const float4*)in)[i];
    ushort4v o;
    o[0] = f2bf(v.x); o[1] = f2bf(v.y); o[2] = f2bf(v.z); o[3] = f2bf(v.w);
    ((ushort4v*)out)[i] = o;
  } else {
    const int gw = (bid - 5120) * 4 + (threadIdx.x >> 6);  // 0..8191 = b*2048+q
    const int l = threadIdx.x & 63;
    const int b = gw >> 11, q = gw & 2047;
    const float* row = adj + ((size_t)b * 2048 + q) * 2048;
    unsigned long long* ob = abits + (size_t)b * 65536 + q;
#pragma unroll 4
    for (int kt = 0; kt < 32; ++kt) {
      const float v = row[kt * 64 + l];
      const unsigned long long m = __ballot(v != 0.f);
      if (l == 0) ob[(size_t)kt * 2048] = m;
    }
  }
}

// ---------------- 128x128 bf16 MFMA GEMM: C = A @ Bt^T (+bias) ----------------
// Double-buffered LDS, one barrier/iter; next-chunk loads issued pre-compute.
// MODE 0: QKV epilogue. nt<4: Q (scaled, bf16); nt in [4,8): K (bf16);
//         nt>=8: V -> f16, LDS-transposed, stored (b,h,d,s) coalesced.
// MODE 1: fp32 + bias epilogue to f_out
template <int MODE>
__global__ __launch_bounds__(256, 3) void gemm128_k(const unsigned short* __restrict__ A,
                                                    const unsigned short* __restrict__ Bt,
                                                    const float* __restrict__ bias, int Kdim,
                                                    int Ntiles, unsigned short* __restrict__ q_out,
                                                    unsigned short* __restrict__ k_out,
                                                    unsigned short* __restrict__ v_out,
                                                    float* __restrict__ f_out) {
  __shared__ union {
    struct { unsigned short A[2][128][40], B[2][128][40]; } s;  // 40 KB
    unsigned short T[64][136];                                  // V-transpose staging
  } u;

  const int t = threadIdx.x;
  const int lane = t & 63, w = t >> 6, ln = lane & 15, quad = lane >> 4;
  const int mt = blockIdx.x / Ntiles, nt = blockIdx.x % Ntiles;
  const int wm = (w >> 1) * 64, wn = (w & 1) * 64;
  const int strow = t >> 2, stcol = (t & 3) * 8;

  const size_t abase = (size_t)(mt * 128 + strow) * Kdim + stcol;
  const size_t bbase = (size_t)(nt * 128 + strow) * Kdim + stcol;

  f32x4 acc[4][4];
#pragma unroll
  for (int i = 0; i < 4; ++i)
#pragma unroll
    for (int j = 0; j < 4; ++j) acc[i][j] = (f32x4){0.f, 0.f, 0.f, 0.f};

  // prologue: load + stage chunk 0 into buf 0
  bf16x8 a0 = *(const bf16x8*)(A + abase);
  bf16x8 a1 = *(const bf16x8*)(A + abase + (size_t)64 * Kdim);
  bf16x8 b0 = *(const bf16x8*)(Bt + bbase);
  bf16x8 b1 = *(const bf16x8*)(Bt + bbase + (size_t)64 * Kdim);
  *(bf16x8*)&u.s.A[0][strow][stcol] = a0;
  *(bf16x8*)&u.s.A[0][64 + strow][stcol] = a1;
  *(bf16x8*)&u.s.B[0][strow][stcol] = b0;
  *(bf16x8*)&u.s.B[0][64 + strow][stcol] = b1;
  __syncthreads();

  const int iters = Kdim >> 5;
  for (int it = 0; it < iters; ++it) {
    const int cur = it & 1, nxt = cur ^ 1;

    // issue next-chunk loads FIRST (drained at the LDS write below)
    const int kn = ((it + 1) << 5) & (Kdim - 1);
    a0 = *(const bf16x8*)(A + abase + kn);
    a1 = *(const bf16x8*)(A + abase + (size_t)64 * Kdim + kn);
    b0 = *(const bf16x8*)(Bt + bbase + kn);
    b1 = *(const bf16x8*)(Bt + bbase + (size_t)64 * Kdim + kn);

    bf16x8 bfr[4];
#pragma unroll
    for (int nf = 0; nf < 4; ++nf)
      bfr[nf] = *(const bf16x8*)&u.s.B[cur][wn + nf * 16 + ln][quad * 8];
#pragma unroll
    for (int mf = 0; mf < 4; ++mf) {
      bf16x8 af = *(const bf16x8*)&u.s.A[cur][wm + mf * 16 + ln][quad * 8];
#pragma unroll
      for (int nf = 0; nf < 4; ++nf)
        acc[mf][nf] = __builtin_amdgcn_mfma_f32_16x16x32_bf16(af, bfr[nf], acc[mf][nf], 0, 0, 0);
    }

    if (it + 1 < iters) {
      *(bf16x8*)&u.s.A[nxt][strow][stcol] = a0;
      *(bf16x8*)&u.s.A[nxt][64 + strow][stcol] = a1;
      *(bf16x8*)&u.s.B[nxt][strow][stcol] = b0;
      *(bf16x8*)&u.s.B[nxt][64 + strow][stcol] = b1;
      __syncthreads();
    }
  }

  // ---------------- epilogue (C layout: col=lane&15, row=quad*4+reg) ----------
  if (MODE == 0 && nt >= 8) {
    // V: LDS transpose -> coalesced V^T rows. Tile = 128 s x 128 d-cols.
    const int bb = mt >> 4, sq0 = (mt & 15) * 128;
#pragma unroll
    for (int half = 0; half < 2; ++half) {
      __syncthreads();  // A/B buffers dead; T aliases them
      if ((w & 1) == half) {
#pragma unroll
        for (int nf = 0; nf < 4; ++nf) {
          const float bv = bias[nt * 128 + half * 64 + nf * 16 + ln];
#pragma unroll
          for (int mf = 0; mf < 4; ++mf)
#pragma unroll
            for (int r = 0; r < 4; ++r)
              u.T[nf * 16 + ln][wm + mf * 16 + quad * 4 + r] = f2h(acc[mf][nf][r] + bv);
        }
      }
      __syncthreads();
#pragma unroll
      for (int rep = 0; rep < 4; ++rep) {
        const int row = rep * 16 + (t >> 4), c = t & 15;
        const bf16x8 val = *(const bf16x8*)&u.T[row][c * 8];
        const int hd = (nt - 8) * 128 + half * 64 + row;
        const int hh = hd >> 6, dd = hd & 63;
        *(bf16x8*)(v_out + ((size_t)(bb * 8 + hh) * 64 + dd) * 2048 + sq0 + c * 8) = val;
      }
    }
    return;
  }

#pragma unroll
  for (int mf = 0; mf < 4; ++mf) {
    const int m = mt * 128 + wm + mf * 16 + quad * 4;
#pragma unroll
    for (int nf = 0; nf < 4; ++nf) {
      const int n = nt * 128 + wn + nf * 16 + ln;
      const float bv = bias[n];
      if (MODE == 0) {
        const int hd = n & 511;
        const int hh = hd >> 6, dd = hd & 63;
        const int bb = m >> 11, sq = m & 2047;
        if (n < 512) {
#pragma unroll
          for (int r = 0; r < 4; ++r)
            q_out[((size_t)(bb * 8 + hh) * 2048 + sq + r) * 64 + dd] =
                f2bf((acc[mf][nf][r] + bv) * QSCALE);
        } else {
#pragma unroll
          for (int r = 0; r < 4; ++r)
            k_out[((size_t)(bb * 8 + hh) * 2048 + sq + r) * 64 + dd] = f2bf(acc[mf][nf][r] + bv);
        }
      } else {
#pragma unroll
        for (int r = 0; r < 4; ++r) f_out[(size_t)(m + r) * 512 + n] = acc[mf][nf][r] + bv;
      }
    }
  }
}

// ---------------- fused flash attention, S^T orientation, dbuf --------------
// grid 512: bh = blk&31, qt = blk>>5. 4 waves x 32 q-rows, BN=64.
// lsum via MFMA ones-column; V-frags hoisted; sbfe mask; packed cvt.
__global__ __launch_bounds__(256, 2) void attn_k(const unsigned short* __restrict__ Qg,
                                                 const unsigned short* __restrict__ Kg,
                                                 const unsigned short* __restrict__ Vg,
                                                 const unsigned long long* __restrict__ Mg,
                                                 unsigned short* __restrict__ Og) {
  __shared__ unsigned short K_lds[2][64][72];   // [buf][key][d] bf16
  __shared__ unsigned short V_lds[2][64][72];   // [buf][d][key] f16
  __shared__ unsigned long long M_lds[2][128];  // [buf][q] mask bits

  const int t = threadIdx.x;
  const int w = t >> 6, lane = t & 63, ln = lane & 15, quad = lane >> 4;
  const int bh = blockIdx.x & 31, qt = blockIdx.x >> 5, bb = bh >> 3;
  const int sbase = qt * 128;

  const unsigned short* Qp = Qg + (size_t)bh * (2048 * 64);
  const unsigned short* Kp = Kg + (size_t)bh * (2048 * 64);
  const unsigned short* Vp = Vg + (size_t)bh * (64 * 2048);
  const unsigned long long* Mp = Mg + (size_t)bb * 65536 + sbase;

  bf16x8 qf[2][2];
#pragma unroll
  for (int qg = 0; qg < 2; ++qg) {
    const int qrow = sbase + w * 32 + qg * 16 + ln;
    qf[qg][0] = *(const bf16x8*)(Qp + (size_t)qrow * 64 + quad * 8);
    qf[qg][1] = *(const bf16x8*)(Qp + (size_t)qrow * 64 + 32 + quad * 8);
  }

  // ones-column B-frag: B[k][n]=1 iff n==0 -> lane ln==0 holds ones
  const _Float16 one_h = (_Float16)((ln == 0) ? 1.0f : 0.0f);
  const f16x4 vf_one = (f16x4){one_h, one_h, one_h, one_h};

  f32x4 acc_o[2][4];
#pragma unroll
  for (int qg = 0; qg < 2; ++qg)
#pragma unroll
    for (int dg = 0; dg < 4; ++dg) acc_o[qg][dg] = (f32x4){0.f, 0.f, 0.f, 0.f};
  f32x4 acc_1[2] = {(f32x4){0.f, 0.f, 0.f, 0.f}, (f32x4){0.f, 0.f, 0.f, 0.f}};

  const int strow = t >> 2;
  const int stcol = (t & 3) * 16;

  // per-lane base pointers (linear; prefetch runs past end on last iter,
  // reads land in adjacent ws buffers -- valid memory, values unused)
  const unsigned short* Kl = Kp + (size_t)strow * 64 + stcol;
  const unsigned short* Vl = Vp + (size_t)strow * 2048 + stcol;

  bf16x8 kr0 = *(const bf16x8*)(Kl);
  bf16x8 kr1 = *(const bf16x8*)(Kl + 8);
  bf16x8 vr0 = *(const bf16x8*)(Vl);
  bf16x8 vr1 = *(const bf16x8*)(Vl + 8);
  unsigned long long mreg = (w < 2) ? Mp[w * 64 + lane] : 0ull;
  *(bf16x8*)&K_lds[0][strow][stcol] = kr0;
  *(bf16x8*)&K_lds[0][strow][stcol + 8] = kr1;
  *(bf16x8*)&V_lds[0][strow][stcol] = vr0;
  *(bf16x8*)&V_lds[0][strow][stcol + 8] = vr1;
  if (w < 2) M_lds[0][w * 64 + lane] = mreg;
  __syncthreads();

  const int mq = w * 32 + ln;          // M_lds row base for this lane
  const int qsh = quad * 4;            // mask pre-shift for this lane

  for (int kt = 0; kt < 32; ++kt) {
    const int cur = kt & 1, nxt = cur ^ 1;

    // next-tile global loads, linear addressing (drained at LDS writes below)
    kr0 = *(const bf16x8*)(Kl + (size_t)(kt + 1) * 4096);
    kr1 = *(const bf16x8*)(Kl + (size_t)(kt + 1) * 4096 + 8);
    vr0 = *(const bf16x8*)(Vl + (kt + 1) * 64);
    vr1 = *(const bf16x8*)(Vl + (kt + 1) * 64 + 8);
    mreg = (w < 2) ? Mp[(size_t)(kt + 1) * 2048 + w * 64 + lane] : 0ull;

    // S^T[key][q] : A = K-frag, B = Q-frag
    f32x4 sc[2][4];
#pragma unroll
    for (int nf = 0; nf < 4; ++nf) {
      bf16x8 kf0 = *(const bf16x8*)&K_lds[cur][nf * 16 + ln][quad * 8];
      bf16x8 kf1 = *(const bf16x8*)&K_lds[cur][nf * 16 + ln][32 + quad * 8];
#pragma unroll
      for (int qg = 0; qg < 2; ++qg) {
        f32x4 z = (f32x4){0.f, 0.f, 0.f, 0.f};
        z = __builtin_amdgcn_mfma_f32_16x16x32_bf16(kf0, qf[qg][0], z, 0, 0, 0);
        sc[qg][nf] = __builtin_amdgcn_mfma_f32_16x16x32_bf16(kf1, qf[qg][1], z, 0, 0, 0);
      }
    }

    // hoist ALL V-frag LDS reads; lgkm waits overlap the exp burst below
    f16x4 vfa[4][4];
#pragma unroll
    for (int ks = 0; ks < 4; ++ks)
#pragma unroll
      for (int dg = 0; dg < 4; ++dg)
        vfa[ks][dg] = *(const f16x4*)&V_lds[cur][dg * 16 + ln][ks * 16 + quad * 4];

    // mask (sign-mask AND) + exp2 -> P in f16 A-frag layout, packed cvt
    f16x4 pa[2][4];
#pragma unroll
    for (int qg = 0; qg < 2; ++qg) {
      const unsigned long long m64 = M_lds[cur][mq + qg * 16];
      const unsigned wlo = (unsigned)m64 >> qsh;
      const unsigned whi = (unsigned)(m64 >> 32) >> qsh;
#pragma unroll
      for (int nf = 0; nf < 4; ++nf) {
        const unsigned wm16 = ((nf & 2) ? whi : wlo) >> ((nf & 1) * 16);
        float p[4];
#pragma unroll
        for (int r = 0; r < 4; ++r) {
          const int se = sbit(wm16, r);
          const float s = __int_as_float(__float_as_int(sc[qg][nf][r]) & se);
          p[r] = EXP2F(s);
        }
        pa[qg][nf] = pk4(p[0], p[1], p[2], p[3]);
      }
    }

    // O += P @ V ; lsum += P @ ones (col 0 of acc_1)
#pragma unroll
    for (int ks = 0; ks < 4; ++ks)
#pragma unroll
      for (int qg = 0; qg < 2; ++qg) {
#pragma unroll
        for (int dg = 0; dg < 4; ++dg)
          acc_o[qg][dg] =
              __builtin_amdgcn_mfma_f32_16x16x16f16(pa[qg][ks], vfa[ks][dg], acc_o[qg][dg], 0, 0, 0);
        acc_1[qg] = __builtin_amdgcn_mfma_f32_16x16x16f16(pa[qg][ks], vf_one, acc_1[qg], 0, 0, 0);
      }

    if (kt < 31) {
      *(bf16x8*)&K_lds[nxt][strow][stcol] = kr0;
      *(bf16x8*)&K_lds[nxt][strow][stcol + 8] = kr1;
      *(bf16x8*)&V_lds[nxt][strow][stcol] = vr0;
      *(bf16x8*)&V_lds[nxt][strow][stcol + 8] = vr1;
      if (w < 2) M_lds[nxt][w * 64 + lane] = mreg;
      __syncthreads();
    }
  }

  // epilogue: lsum for row q=quad*4+r lives in acc_1[qg][r] at lanes ln==0
  unsigned short* Op = Og + (size_t)bb * 2048 * 512 + (size_t)(bh & 7) * 64;
#pragma unroll
  for (int qg = 0; qg < 2; ++qg)
#pragma unroll
    for (int r = 0; r < 4; ++r) {
      const float inv = 1.0f / __shfl(acc_1[qg][r], quad * 16);
      const int sq = sbase + w * 32 + qg * 16 + quad * 4 + r;
#pragma unroll
      for (int dg = 0; dg < 4; ++dg)
        Op[(size_t)sq * 512 + dg * 16 + ln] = f2bf(acc_o[qg][dg][r] * inv);
    }
}

// ---------------------------------------------------------------------------
extern "C" void kernel_launch(void* const* d_in, const int* in_sizes, int n_in, void* d_out,
                              int out_size, void* d_ws, size_t ws_size, hipStream_t stream) {
  const float* x = (const float*)d_in[0];
  const float* adj = (const float*)d_in[1];
  const float* wqkv = (const float*)d_in[2];
  const float* bqkv = (const float*)d_in[3];
  const float* outw = (const float*)d_in[4];
  const float* outb = (const float*)d_in[5];
  float* out = (float*)d_out;

  char* ws = (char*)d_ws;
  unsigned short* x_bf = (unsigned short*)(ws);                      //  8.0 MB
  unsigned short* wqkv_bf = (unsigned short*)(ws + 8388608);         //  1.5 MB
  unsigned short* outw_bf = (unsigned short*)(ws + 9961472);         //  0.5 MB
  unsigned long long* abits = (unsigned long long*)(ws + 10485760);  //  2.0 MB
  unsigned short* Qb = (unsigned short*)(ws + 27262976);             //  8.0 MB (b,h,s,d) bf16
  unsigned short* Kb = (unsigned short*)(ws + 35651584);             //  8.0 MB (b,h,s,d) bf16
  unsigned short* Vb = (unsigned short*)(ws + 44040192);             //  8.0 MB (b,h,d,s) f16
  unsigned short* Ob = (unsigned short*)(ws + 52428800);             //  8.0 MB (b,s,e) bf16

  prep_k<<<7168, 256, 0, stream>>>(x, x_bf, wqkv, wqkv_bf, outw, outw_bf, adj, abits);

  gemm128_k<0><<<768, 256, 0, stream>>>(x_bf, wqkv_bf, bqkv, 512, 12, Qb, Kb, Vb, nullptr);

  attn_k<<<512, 256, 0, stream>>>(Qb, Kb, Vb, abits, Ob);

  gemm128_k<1><<<256, 256, 0, stream>>>(Ob, outw_bf, outb, 512, 4, nullptr, nullptr, nullptr, out);
}

// Round 11
// 215.695 us; speedup vs baseline: 1.1718x; 1.0204x over previous
//
#include <hip/hip_runtime.h>

// ---------------------------------------------------------------------------
// MultiHeadAttention: x(4,2048,512) fp32, adj(4,2048,2048) 0/1 fp32
// R11: PV MFMA K=16 -> K=32 via permuted S^T key mapping (K-frag loads
// permuted K_lds rows so C rows land in 16x16x32 A-slot order). PV 40->20
// MFMAs, ones 8->4, V-frags 16xb64 -> 8xb128. K_lds stride 76 (2-way free
// for the permuted row set). Gemms: XCD-local mt grouping (blk&7 swizzle).
// ---------------------------------------------------------------------------

typedef __attribute__((ext_vector_type(8))) short bf16x8;
typedef __attribute__((ext_vector_type(4))) float f32x4;
typedef __attribute__((ext_vector_type(4))) unsigned short ushort4v;
typedef __attribute__((ext_vector_type(4))) _Float16 f16x4;
typedef __attribute__((ext_vector_type(8))) _Float16 f16x8;
typedef __attribute__((ext_vector_type(2))) __fp16 h16x2;  // cvt_pkrtz return type

#if __has_builtin(__builtin_amdgcn_exp2f)
#define EXP2F(x) __builtin_amdgcn_exp2f(x)
#else
#define EXP2F(x) exp2f(x)
#endif

// 0.125 (1/sqrt(64)) * log2(e), folded into Q at the QKV-gemm epilogue
#define QSCALE 0.18033688011112042f

__device__ __forceinline__ unsigned short f2bf(float f) {
  unsigned int u = __float_as_uint(f);
  u += 0x7FFFu + ((u >> 16) & 1u);
  return (unsigned short)(u >> 16);
}
__device__ __forceinline__ unsigned short f2h(float f) {
  union { _Float16 h; unsigned short u; } cv;
  cv.h = (_Float16)f;
  return cv.u;
}

// sign-extend bit (pos) of w to 0 / 0xFFFFFFFF
__device__ __forceinline__ int sbit(unsigned w, int pos) {
  return ((int)(w << (31 - pos))) >> 31;  // compiler emits v_bfe_i32
}

// pack 8 floats -> f16x8 via 4 packed RTZ converts
__device__ __forceinline__ f16x8 pk8(const float* p) {
  union { struct { h16x2 a, b, c, d; } s; f16x8 v; } u;
  u.s.a = __builtin_amdgcn_cvt_pkrtz(p[0], p[1]);
  u.s.b = __builtin_amdgcn_cvt_pkrtz(p[2], p[3]);
  u.s.c = __builtin_amdgcn_cvt_pkrtz(p[4], p[5]);
  u.s.d = __builtin_amdgcn_cvt_pkrtz(p[6], p[7]);
  return u.v;
}

// PV matmul: K=32 f16 (slot pairing identical in A and B, so a two-K=16
// fallback is mathematically identical if the builtin is absent)
__device__ __forceinline__ f32x4 mfma_pv(f16x8 a, f16x8 b, f32x4 c) {
#if __has_builtin(__builtin_amdgcn_mfma_f32_16x16x32_f16)
  return __builtin_amdgcn_mfma_f32_16x16x32_f16(a, b, c, 0, 0, 0);
#else
  union { f16x8 v; struct { f16x4 lo, hi; } s; } ua, ub;
  ua.v = a; ub.v = b;
  c = __builtin_amdgcn_mfma_f32_16x16x16f16(ua.s.lo, ub.s.lo, c, 0, 0, 0);
  return __builtin_amdgcn_mfma_f32_16x16x16f16(ua.s.hi, ub.s.hi, c, 0, 0, 0);
#endif
}

// ---------------- fused prep: casts + adj bit-pack, one launch ---------------
__global__ __launch_bounds__(256) void prep_k(const float* __restrict__ x,
                                              unsigned short* __restrict__ x_bf,
                                              const float* __restrict__ wqkv,
                                              unsigned short* __restrict__ wqkv_bf,
                                              const float* __restrict__ outw,
                                              unsigned short* __restrict__ outw_bf,
                                              const float* __restrict__ adj,
                                              unsigned long long* __restrict__ abits) {
  const int bid = blockIdx.x;
  if (bid < 5120) {
    const float* in; unsigned short* out; int i;
    if (bid < 4096) { in = x; out = x_bf; i = bid * 256 + threadIdx.x; }
    else if (bid < 4864) { in = wqkv; out = wqkv_bf; i = (bid - 4096) * 256 + threadIdx.x; }
    else { in = outw; out = outw_bf; i = (bid - 4864) * 256 + threadIdx.x; }
    float4 v = ((const float4*)in)[i];
    ushort4v o;
    o[0] = f2bf(v.x); o[1] = f2bf(v.y); o[2] = f2bf(v.z); o[3] = f2bf(v.w);
    ((ushort4v*)out)[i] = o;
  } else {
    const int gw = (bid - 5120) * 4 + (threadIdx.x >> 6);  // 0..8191 = b*2048+q
    const int l = threadIdx.x & 63;
    const int b = gw >> 11, q = gw & 2047;
    const float* row = adj + ((size_t)b * 2048 + q) * 2048;
    unsigned long long* ob = abits + (size_t)b * 65536 + q;
#pragma unroll 4
    for (int kt = 0; kt < 32; ++kt) {
      const float v = row[kt * 64 + l];
      const unsigned long long m = __ballot(v != 0.f);
      if (l == 0) ob[(size_t)kt * 2048] = m;
    }
  }
}

// ---------------- 128x128 bf16 MFMA GEMM: C = A @ Bt^T (+bias) ----------------
// XCD-local tiling: blk&7 = XCD; each XCD owns a contiguous mt range so its
// L2 reuses A rows across all nt. Double-buffered LDS, one barrier/iter.
// MODE 0: QKV epilogue (Q scaled bf16 / K bf16 / V f16 LDS-transposed).
// MODE 1: fp32 + bias epilogue to f_out
template <int MODE>
__global__ __launch_bounds__(256, 3) void gemm128_k(const unsigned short* __restrict__ A,
                                                    const unsigned short* __restrict__ Bt,
                                                    const float* __restrict__ bias, int Kdim,
                                                    int Ntiles, unsigned short* __restrict__ q_out,
                                                    unsigned short* __restrict__ k_out,
                                                    unsigned short* __restrict__ v_out,
                                                    float* __restrict__ f_out) {
  __shared__ union {
    struct { unsigned short A[2][128][40], B[2][128][40]; } s;  // 40 KB
    unsigned short T[64][136];                                  // V-transpose staging
  } u;

  const int t = threadIdx.x;
  const int lane = t & 63, w = t >> 6, ln = lane & 15, quad = lane >> 4;
  // XCD-local mt grouping (round-robin blk->XCD assumed; speed-only heuristic)
  const int xcd = blockIdx.x & 7, loc = blockIdx.x >> 3;
  const int mt = xcd * ((gridDim.x >> 3) / Ntiles) + loc / Ntiles;
  const int nt = loc % Ntiles;
  const int wm = (w >> 1) * 64, wn = (w & 1) * 64;
  const int strow = t >> 2, stcol = (t & 3) * 8;

  const size_t abase = (size_t)(mt * 128 + strow) * Kdim + stcol;
  const size_t bbase = (size_t)(nt * 128 + strow) * Kdim + stcol;

  f32x4 acc[4][4];
#pragma unroll
  for (int i = 0; i < 4; ++i)
#pragma unroll
    for (int j = 0; j < 4; ++j) acc[i][j] = (f32x4){0.f, 0.f, 0.f, 0.f};

  // prologue: load + stage chunk 0 into buf 0
  bf16x8 a0 = *(const bf16x8*)(A + abase);
  bf16x8 a1 = *(const bf16x8*)(A + abase + (size_t)64 * Kdim);
  bf16x8 b0 = *(const bf16x8*)(Bt + bbase);
  bf16x8 b1 = *(const bf16x8*)(Bt + bbase + (size_t)64 * Kdim);
  *(bf16x8*)&u.s.A[0][strow][stcol] = a0;
  *(bf16x8*)&u.s.A[0][64 + strow][stcol] = a1;
  *(bf16x8*)&u.s.B[0][strow][stcol] = b0;
  *(bf16x8*)&u.s.B[0][64 + strow][stcol] = b1;
  __syncthreads();

  const int iters = Kdim >> 5;
  for (int it = 0; it < iters; ++it) {
    const int cur = it & 1, nxt = cur ^ 1;

    // issue next-chunk loads FIRST (drained at the LDS write below)
    const int kn = ((it + 1) << 5) & (Kdim - 1);
    a0 = *(const bf16x8*)(A + abase + kn);
    a1 = *(const bf16x8*)(A + abase + (size_t)64 * Kdim + kn);
    b0 = *(const bf16x8*)(Bt + bbase + kn);
    b1 = *(const bf16x8*)(Bt + bbase + (size_t)64 * Kdim + kn);

    bf16x8 bfr[4];
#pragma unroll
    for (int nf = 0; nf < 4; ++nf)
      bfr[nf] = *(const bf16x8*)&u.s.B[cur][wn + nf * 16 + ln][quad * 8];
#pragma unroll
    for (int mf = 0; mf < 4; ++mf) {
      bf16x8 af = *(const bf16x8*)&u.s.A[cur][wm + mf * 16 + ln][quad * 8];
#pragma unroll
      for (int nf = 0; nf < 4; ++nf)
        acc[mf][nf] = __builtin_amdgcn_mfma_f32_16x16x32_bf16(af, bfr[nf], acc[mf][nf], 0, 0, 0);
    }

    if (it + 1 < iters) {
      *(bf16x8*)&u.s.A[nxt][strow][stcol] = a0;
      *(bf16x8*)&u.s.A[nxt][64 + strow][stcol] = a1;
      *(bf16x8*)&u.s.B[nxt][strow][stcol] = b0;
      *(bf16x8*)&u.s.B[nxt][64 + strow][stcol] = b1;
      __syncthreads();
    }
  }

  // ---------------- epilogue (C layout: col=lane&15, row=quad*4+reg) ----------
  if (MODE == 0 && nt >= 8) {
    // V: LDS transpose -> coalesced V^T rows. Tile = 128 s x 128 d-cols.
    const int bb = mt >> 4, sq0 = (mt & 15) * 128;
#pragma unroll
    for (int half = 0; half < 2; ++half) {
      __syncthreads();  // A/B buffers dead; T aliases them
      if ((w & 1) == half) {
#pragma unroll
        for (int nf = 0; nf < 4; ++nf) {
          const float bv = bias[nt * 128 + half * 64 + nf * 16 + ln];
#pragma unroll
          for (int mf = 0; mf < 4; ++mf)
#pragma unroll
            for (int r = 0; r < 4; ++r)
              u.T[nf * 16 + ln][wm + mf * 16 + quad * 4 + r] = f2h(acc[mf][nf][r] + bv);
        }
      }
      __syncthreads();
#pragma unroll
      for (int rep = 0; rep < 4; ++rep) {
        const int row = rep * 16 + (t >> 4), c = t & 15;
        const bf16x8 val = *(const bf16x8*)&u.T[row][c * 8];
        const int hd = (nt - 8) * 128 + half * 64 + row;
        const int hh = hd >> 6, dd = hd & 63;
        *(bf16x8*)(v_out + ((size_t)(bb * 8 + hh) * 64 + dd) * 2048 + sq0 + c * 8) = val;
      }
    }
    return;
  }

#pragma unroll
  for (int mf = 0; mf < 4; ++mf) {
    const int m = mt * 128 + wm + mf * 16 + quad * 4;
#pragma unroll
    for (int nf = 0; nf < 4; ++nf) {
      const int n = nt * 128 + wn + nf * 16 + ln;
      const float bv = bias[n];
      if (MODE == 0) {
        const int hd = n & 511;
        const int hh = hd >> 6, dd = hd & 63;
        const int bb = m >> 11, sq = m & 2047;
        if (n < 512) {
#pragma unroll
          for (int r = 0; r < 4; ++r)
            q_out[((size_t)(bb * 8 + hh) * 2048 + sq + r) * 64 + dd] =
                f2bf((acc[mf][nf][r] + bv) * QSCALE);
        } else {
#pragma unroll
          for (int r = 0; r < 4; ++r)
            k_out[((size_t)(bb * 8 + hh) * 2048 + sq + r) * 64 + dd] = f2bf(acc[mf][nf][r] + bv);
        }
      } else {
#pragma unroll
        for (int r = 0; r < 4; ++r) f_out[(size_t)(m + r) * 512 + n] = acc[mf][nf][r] + bv;
      }
    }
  }
}

// ---------------- fused flash attention, S^T orientation, dbuf, K=32 PV -----
// grid 512: bh = blk&31, qt = blk>>5. 4 waves x 32 q-rows, BN=64.
// Permuted key mapping: QK^T K-frag (h,e) loads K_lds row
// h*32 + (ln>>2)*8 + e*4 + (ln&3), so C rows hold keys h*32+quad*8+e*4+r --
// the A-slot order of mfma 16x16x32 f16. PV: 2h x 2qg x (4dg+ones) = 20 MFMA.
__global__ __launch_bounds__(256, 2) void attn_k(const unsigned short* __restrict__ Qg,
                                                 const unsigned short* __restrict__ Kg,
                                                 const unsigned short* __restrict__ Vg,
                                                 const unsigned long long* __restrict__ Mg,
                                                 unsigned short* __restrict__ Og) {
  __shared__ unsigned short K_lds[2][64][76];   // [buf][key][d] bf16; 76: permuted rows 2-way
  __shared__ unsigned short V_lds[2][64][72];   // [buf][d][key] f16
  __shared__ unsigned long long M_lds[2][128];  // [buf][q] mask bits

  const int t = threadIdx.x;
  const int w = t >> 6, lane = t & 63, ln = lane & 15, quad = lane >> 4;
  const int bh = blockIdx.x & 31, qt = blockIdx.x >> 5, bb = bh >> 3;
  const int sbase = qt * 128;

  const unsigned short* Qp = Qg + (size_t)bh * (2048 * 64);
  const unsigned short* Kp = Kg + (size_t)bh * (2048 * 64);
  const unsigned short* Vp = Vg + (size_t)bh * (64 * 2048);
  const unsigned long long* Mp = Mg + (size_t)bb * 65536 + sbase;

  bf16x8 qf[2][2];
#pragma unroll
  for (int qg = 0; qg < 2; ++qg) {
    const int qrow = sbase + w * 32 + qg * 16 + ln;
    qf[qg][0] = *(const bf16x8*)(Qp + (size_t)qrow * 64 + quad * 8);
    qf[qg][1] = *(const bf16x8*)(Qp + (size_t)qrow * 64 + 32 + quad * 8);
  }

  // ones B-frag (K=32): B[k][n]=1 iff n==0 -> lane ln==0 holds 8 ones
  const _Float16 one_h = (_Float16)((ln == 0) ? 1.0f : 0.0f);
  const f16x8 vf_one = (f16x8){one_h, one_h, one_h, one_h, one_h, one_h, one_h, one_h};

  f32x4 acc_o[2][4];
#pragma unroll
  for (int qg = 0; qg < 2; ++qg)
#pragma unroll
    for (int dg = 0; dg < 4; ++dg) acc_o[qg][dg] = (f32x4){0.f, 0.f, 0.f, 0.f};
  f32x4 acc_1[2] = {(f32x4){0.f, 0.f, 0.f, 0.f}, (f32x4){0.f, 0.f, 0.f, 0.f}};

  const int strow = t >> 2;
  const int stcol = (t & 3) * 16;

  // per-lane base pointers (linear; last-iter prefetch reads adjacent ws)
  const unsigned short* Kl = Kp + (size_t)strow * 64 + stcol;
  const unsigned short* Vl = Vp + (size_t)strow * 2048 + stcol;

  bf16x8 kr0 = *(const bf16x8*)(Kl);
  bf16x8 kr1 = *(const bf16x8*)(Kl + 8);
  bf16x8 vr0 = *(const bf16x8*)(Vl);
  bf16x8 vr1 = *(const bf16x8*)(Vl + 8);
  unsigned long long mreg = (w < 2) ? Mp[w * 64 + lane] : 0ull;
  *(bf16x8*)&K_lds[0][strow][stcol] = kr0;
  *(bf16x8*)&K_lds[0][strow][stcol + 8] = kr1;
  *(bf16x8*)&V_lds[0][strow][stcol] = vr0;
  *(bf16x8*)&V_lds[0][strow][stcol + 8] = vr1;
  if (w < 2) M_lds[0][w * 64 + lane] = mreg;
  __syncthreads();

  const int mq = w * 32 + ln;                                // M_lds row base
  const int kperm = ((ln >> 2) << 3) + (ln & 3);             // permuted K row base

  for (int kt = 0; kt < 32; ++kt) {
    const int cur = kt & 1, nxt = cur ^ 1;

    // next-tile global loads, linear addressing (drained at LDS writes below)
    kr0 = *(const bf16x8*)(Kl + (size_t)(kt + 1) * 4096);
    kr1 = *(const bf16x8*)(Kl + (size_t)(kt + 1) * 4096 + 8);
    vr0 = *(const bf16x8*)(Vl + (kt + 1) * 64);
    vr1 = *(const bf16x8*)(Vl + (kt + 1) * 64 + 8);
    mreg = (w < 2) ? Mp[(size_t)(kt + 1) * 2048 + w * 64 + lane] : 0ull;

    // S^T with permuted key rows: frag f=h*2+e covers keys h*32+quad*8+e*4+r
    f32x4 sc[2][4];
#pragma unroll
    for (int h = 0; h < 2; ++h)
#pragma unroll
      for (int e = 0; e < 2; ++e) {
        const int krow = h * 32 + kperm + e * 4;
        bf16x8 kf0 = *(const bf16x8*)&K_lds[cur][krow][quad * 8];
        bf16x8 kf1 = *(const bf16x8*)&K_lds[cur][krow][32 + quad * 8];
#pragma unroll
        for (int qg = 0; qg < 2; ++qg) {
          f32x4 z = (f32x4){0.f, 0.f, 0.f, 0.f};
          z = __builtin_amdgcn_mfma_f32_16x16x32_bf16(kf0, qf[qg][0], z, 0, 0, 0);
          sc[qg][h * 2 + e] = __builtin_amdgcn_mfma_f32_16x16x32_bf16(kf1, qf[qg][1], z, 0, 0, 0);
        }
      }

    // hoist V-frags (b128): B[k=quad*8+j][n=d] = V_lds[d][h*32+quad*8+j]
    f16x8 vfa[2][4];
#pragma unroll
    for (int h = 0; h < 2; ++h)
#pragma unroll
      for (int dg = 0; dg < 4; ++dg)
        vfa[h][dg] = *(const f16x8*)&V_lds[cur][dg * 16 + ln][h * 32 + quad * 8];

    // mask (sign-mask AND) + exp2 -> P in K=32 A-slot order, packed cvt
    f16x8 pa[2][2];
#pragma unroll
    for (int qg = 0; qg < 2; ++qg) {
      const unsigned long long m64 = M_lds[cur][mq + qg * 16];
#pragma unroll
      for (int h = 0; h < 2; ++h) {
        const unsigned wrd = (h ? (unsigned)(m64 >> 32) : (unsigned)m64) >> (quad * 8);
        float p[8];
#pragma unroll
        for (int e = 0; e < 2; ++e)
#pragma unroll
          for (int r = 0; r < 4; ++r) {
            const int j = e * 4 + r;
            const int se = sbit(wrd, j);
            const float s = __int_as_float(__float_as_int(sc[qg][h * 2 + e][r]) & se);
            p[j] = EXP2F(s);
          }
        pa[qg][h] = pk8(p);
      }
    }

    // O += P @ V (K=32) ; lsum += P @ ones (col 0 of acc_1)
#pragma unroll
    for (int h = 0; h < 2; ++h)
#pragma unroll
      for (int qg = 0; qg < 2; ++qg) {
#pragma unroll
        for (int dg = 0; dg < 4; ++dg)
          acc_o[qg][dg] = mfma_pv(pa[qg][h], vfa[h][dg], acc_o[qg][dg]);
        acc_1[qg] = mfma_pv(pa[qg][h], vf_one, acc_1[qg]);
      }

    if (kt < 31) {
      *(bf16x8*)&K_lds[nxt][strow][stcol] = kr0;
      *(bf16x8*)&K_lds[nxt][strow][stcol + 8] = kr1;
      *(bf16x8*)&V_lds[nxt][strow][stcol] = vr0;
      *(bf16x8*)&V_lds[nxt][strow][stcol + 8] = vr1;
      if (w < 2) M_lds[nxt][w * 64 + lane] = mreg;
      __syncthreads();
    }
  }

  // epilogue: lsum for row q=quad*4+r lives in acc_1[qg][r] at lanes ln==0
  unsigned short* Op = Og + (size_t)bb * 2048 * 512 + (size_t)(bh & 7) * 64;
#pragma unroll
  for (int qg = 0; qg < 2; ++qg)
#pragma unroll
    for (int r = 0; r < 4; ++r) {
      const float inv = 1.0f / __shfl(acc_1[qg][r], quad * 16);
      const int sq = sbase + w * 32 + qg * 16 + quad * 4 + r;
#pragma unroll
      for (int dg = 0; dg < 4; ++dg)
        Op[(size_t)sq * 512 + dg * 16 + ln] = f2bf(acc_o[qg][dg][r] * inv);
    }
}

// ---------------------------------------------------------------------------
extern "C" void kernel_launch(void* const* d_in, const int* in_sizes, int n_in, void* d_out,
                              int out_size, void* d_ws, size_t ws_size, hipStream_t stream) {
  const float* x = (const float*)d_in[0];
  const float* adj = (const float*)d_in[1];
  const float* wqkv = (const float*)d_in[2];
  const float* bqkv = (const float*)d_in[3];
  const float* outw = (const float*)d_in[4];
  const float* outb = (const float*)d_in[5];
  float* out = (float*)d_out;

  char* ws = (char*)d_ws;
  unsigned short* x_bf = (unsigned short*)(ws);                      //  8.0 MB
  unsigned short* wqkv_bf = (unsigned short*)(ws + 8388608);         //  1.5 MB
  unsigned short* outw_bf = (unsigned short*)(ws + 9961472);         //  0.5 MB
  unsigned long long* abits = (unsigned long long*)(ws + 10485760);  //  2.0 MB
  unsigned short* Qb = (unsigned short*)(ws + 27262976);             //  8.0 MB (b,h,s,d) bf16
  unsigned short* Kb = (unsigned short*)(ws + 35651584);             //  8.0 MB (b,h,s,d) bf16
  unsigned short* Vb = (unsigned short*)(ws + 44040192);             //  8.0 MB (b,h,d,s) f16
  unsigned short* Ob = (unsigned short*)(ws + 52428800);             //  8.0 MB (b,s,e) bf16

  prep_k<<<7168, 256, 0, stream>>>(x, x_bf, wqkv, wqkv_bf, outw, outw_bf, adj, abits);

  gemm128_k<0><<<768, 256, 0, stream>>>(x_bf, wqkv_bf, bqkv, 512, 12, Qb, Kb, Vb, nullptr);

  attn_k<<<512, 256, 0, stream>>>(Qb, Kb, Vb, abits, Ob);

  gemm128_k<1><<<256, 256, 0, stream>>>(Ob, outw_bf, outb, 512, 4, nullptr, nullptr, nullptr, out);
}